// Round 9
// baseline (281.577 us; speedup 1.0000x reference)
//
#include <hip/hip_runtime.h>
#include <math.h>

#define B_  32
#define S_  4096
#define E_  256
#define A_  256
#define DE_ 512

typedef __attribute__((ext_vector_type(8))) short short8;
typedef __attribute__((ext_vector_type(4))) float f32x4;

__device__ inline unsigned short f2bf(float x) {
    unsigned int u = __float_as_uint(x);
    u += 0x7FFFu + ((u >> 16) & 1u);      // round-to-nearest-even
    return (unsigned short)(u >> 16);
}
__device__ inline float tanh_fast(float x) {
    x = fminf(fmaxf(x, -15.f), 15.f);
    float t = __expf(2.f * x);
    return (t - 1.f) * __builtin_amdgcn_rcpf(t + 1.f);
}

#define LO_UNITS 1088   // lo-plane offset in 16B units within eo_hl

// convert 8 floats to hi(trunc)/lo(RNE residual) bf16 planes; ds_write to
// unit eu (hi) and LO_UNITS+eu (lo). hi+lo reconstructs x to ~2^-17 rel.
__device__ __forceinline__ void conv_write(float4 v0, float4 v1,
                                           unsigned short* buf, int eu,
                                           float& nacc)
{
    nacc += v0.x*v0.x + v0.y*v0.y + v0.z*v0.z + v0.w*v0.w
          + v1.x*v1.x + v1.y*v1.y + v1.z*v1.z + v1.w*v1.w;
    float xs[8] = {v0.x, v0.y, v0.z, v0.w, v1.x, v1.y, v1.z, v1.w};
    unsigned int hp[4], lp[4];
    #pragma unroll
    for (int j = 0; j < 4; ++j) {
        unsigned int u0 = __float_as_uint(xs[2*j])   & 0xFFFF0000u;
        unsigned int u1 = __float_as_uint(xs[2*j+1]) & 0xFFFF0000u;
        hp[j] = (u0 >> 16) | u1;
        lp[j] = (unsigned int)f2bf(xs[2*j]   - __uint_as_float(u0))
              | ((unsigned int)f2bf(xs[2*j+1] - __uint_as_float(u1)) << 16);
    }
    *(uint4*)&buf[(size_t)eu * 8]              = make_uint4(hp[0], hp[1], hp[2], hp[3]);
    *(uint4*)&buf[(size_t)(LO_UNITS + eu) * 8] = make_uint4(lp[0], lp[1], lp[2], lp[3]);
}

// ---- Prep: block 0..63 = pack We hi/lo bf16 (fragment order),
//            block 64..95 = proj.
__global__ __launch_bounds__(256) void prep_kernel(
    const float* __restrict__ W, const float* __restrict__ dh,
    const float* __restrict__ bias, unsigned short* __restrict__ wepk,
    float* __restrict__ proj)
{
    __shared__ float dh_lds[E_];
    const int bk  = blockIdx.x;
    const int tid = threadIdx.x;
    if (bk < 64) {
        // unit = c*2048 + plane*1024 + kg*256 + a; 8 bf16 = We[a][c*32+kg*8..+8]
        const int idx = bk * 256 + tid;
        const int c     = idx >> 11;
        const int r     = idx & 2047;
        const int plane = r >> 10;
        const int kg    = (r >> 8) & 3;
        const int a     = r & 255;
        const float* src = W + (size_t)a * DE_ + E_ + c * 32 + kg * 8;
        unsigned int pk[4];
        #pragma unroll
        for (int j = 0; j < 4; ++j) {
            float x0 = src[2 * j], x1 = src[2 * j + 1];
            unsigned int u0 = __float_as_uint(x0) & 0xFFFF0000u;
            unsigned int u1 = __float_as_uint(x1) & 0xFFFF0000u;
            if (plane) {
                unsigned short l0 = f2bf(x0 - __uint_as_float(u0));
                unsigned short l1 = f2bf(x1 - __uint_as_float(u1));
                pk[j] = (unsigned int)l0 | ((unsigned int)l1 << 16);
            } else {
                pk[j] = (u0 >> 16) | u1;
            }
        }
        *(uint4*)&wepk[(size_t)idx * 8] = make_uint4(pk[0], pk[1], pk[2], pk[3]);
    } else {
        const int b = bk - 64;
        const int a = tid;
        dh_lds[a] = dh[b * E_ + a];
        __syncthreads();
        float acc = bias[a];
        const float* wrow = W + (size_t)a * DE_;
        #pragma unroll
        for (int d = 0; d < E_; d += 4) {
            float4 w = *(const float4*)(wrow + d);
            acc += dh_lds[d] * w.x + dh_lds[d+1] * w.y
                 + dh_lds[d+2] * w.z + dh_lds[d+3] * w.w;
        }
        proj[b * A_ + a] = acc;
    }
}

// ---- Scores v11: TS=32, FULL-K LDS residency, BARRIER-FREE K-loop.
// The 32-row x 256-K hi/lo bf16 tile (34.8 KB) is staged ONCE (8 deep
// float4 loads/thread, convert, ds_write), then ONE __syncthreads, then
// the entire matmul (192 MFMA + 32 ds_read_b128 + 64 We loads per wave)
// runs as a single straight-line region with zero barriers — the compiler
// pipelines lgkm/vmcnt across the whole K like the m97 inner loop, instead
// of 8 barrier-chopped phases (the 25%-MfmaUtil structure of R0-R8).
// LDS layout: unit = c*136 + kg*34 + r (hi), +LO_UNITS (lo); b128 reads
// conflict-free (16 consecutive-lr lanes -> consecutive 16B units).
// acc = 32 AGPRs; 45.7 KB LDS -> 3 blocks/CU, 3 waves/SIMD.
__global__ __launch_bounds__(256, 3) void scores_kernel(
    const float* __restrict__ eo, const unsigned short* __restrict__ wepk,
    const float* __restrict__ proj,
    float* __restrict__ scores, float* __restrict__ nsq,
    float* __restrict__ Pbuf)
{
    // [0,34816): eo hi/lo (2176 units x 16 B)
    // [34816,43520): red4 [64][34] f32 | [43520,44544): npart[256]
    // [44544,45568): qpart[256]       | [45568,45696): wsb[32]
    __shared__ __align__(16) unsigned char pool[45696];
    unsigned short* eo_hl = (unsigned short*)pool;

    const int tid = threadIdx.x;
    const int b   = blockIdx.x & (B_ - 1);
    const int s0  = (blockIdx.x >> 5) * 32;
    const int w   = tid >> 6, l = tid & 63;   // w = a-block of this wave
    const int lq  = l >> 4,  lr = l & 15;

    // We fragment unit (16B units): c*2048 + plane*1024 + lq*256 + (w*64+nt*16+lr)
    const int wunit = lq * 256 + w * 64 + lr;

    f32x4 acc[2][4];
    #pragma unroll
    for (int i = 0; i < 2; ++i)
        #pragma unroll
        for (int j = 0; j < 4; ++j)
            acc[i][j] = (f32x4){0.f, 0.f, 0.f, 0.f};
    float nacc = 0.f;

    float pr[4];
    #pragma unroll
    for (int nt = 0; nt < 4; ++nt) pr[nt] = proj[b * A_ + w * 64 + nt * 16 + lr];

    // ---- stage ALL K: thread = (row sr, chunk scg); 128 B contiguous/thread
    {
        const int sr  = tid >> 3;     // 0..31
        const int scg = tid & 7;      // chunk staged by this thread
        const float* gsrc = eo + (size_t)(s0 + sr) * (B_ * E_) + b * E_ + scg * 32;
        float4 v[8];
        #pragma unroll
        for (int q = 0; q < 8; ++q) v[q] = *(const float4*)(gsrc + q * 4);
        #pragma unroll
        for (int kg = 0; kg < 4; ++kg)
            conv_write(v[2*kg], v[2*kg+1], eo_hl, scg * 136 + kg * 34 + sr, nacc);
    }
    __syncthreads();   // the ONLY barrier before the epilogue

    // ---- barrier-free K-loop: 8 chunks x (8 We loads + 4 ds_read + 24 MFMA)
    for (int c = 0; c < 8; ++c) {
        short8 bh[4], bl[4];
        const unsigned short* wsrc = wepk + ((size_t)c * 2048 + wunit) * 8;
        #pragma unroll
        for (int nt = 0; nt < 4; ++nt) {
            bh[nt] = *(const short8*)(wsrc + (size_t)(nt * 16) * 8);
            bl[nt] = *(const short8*)(wsrc + (size_t)(1024 + nt * 16) * 8);
        }
        #pragma unroll
        for (int mt = 0; mt < 2; ++mt) {
            const int au = c * 136 + lq * 34 + mt * 16 + lr;
            short8 ah = *(const short8*)&eo_hl[(size_t)au * 8];
            short8 al = *(const short8*)&eo_hl[(size_t)(LO_UNITS + au) * 8];
            #pragma unroll
            for (int nt = 0; nt < 4; ++nt) {
                acc[mt][nt] = __builtin_amdgcn_mfma_f32_16x16x32_bf16(ah, bh[nt], acc[mt][nt], 0, 0, 0);
                acc[mt][nt] = __builtin_amdgcn_mfma_f32_16x16x32_bf16(ah, bl[nt], acc[mt][nt], 0, 0, 0);
                acc[mt][nt] = __builtin_amdgcn_mfma_f32_16x16x32_bf16(al, bh[nt], acc[mt][nt], 0, 0, 0);
            }
        }
    }

    // ---- epilogue: tanh + reduce over a (scratch does NOT overlay hi/lo —
    // the fused-attend P pass below still needs the full eo tile)
    float* red4  = (float*)(pool + 34816);   // [64 a-groups][34]
    float* npart = (float*)(pool + 43520);   // 256
    float* qpart = (float*)(pool + 44544);   // 256
    float* wsb   = (float*)(pool + 45568);   // 32
    #pragma unroll
    for (int mt = 0; mt < 2; ++mt) {
        #pragma unroll
        for (int r = 0; r < 4; ++r) {
            float s = 0.f;
            #pragma unroll
            for (int nt = 0; nt < 4; ++nt)
                s += tanh_fast(pr[nt] + acc[mt][nt][r]);
            // C/D layout: col = lr (a-dim), row = mt*16 + lq*4 + r (s-dim)
            red4[(w * 16 + lr) * 34 + (mt * 16 + lq * 4 + r)] = s;
        }
    }
    npart[tid] = nacc;    // partial of (row tid>>3, chunk tid&7)
    __syncthreads();
    {   // (row = tid>>3, e8 = tid&7) sums 8 of 64 a-groups
        const int row = tid >> 3, e8 = tid & 7;
        float s = 0.f;
        #pragma unroll
        for (int j = 0; j < 8; ++j) s += red4[(e8 * 8 + j) * 34 + row];
        qpart[e8 * 32 + row] = s;
    }
    __syncthreads();
    if (tid < 32) {
        float sc = 0.f;
        #pragma unroll
        for (int e = 0; e < 8; ++e) sc += qpart[e * 32 + tid];
        scores[b * S_ + s0 + tid] = sc;
        float nn = 0.f;
        #pragma unroll
        for (int cc = 0; cc < 8; ++cc) nn += npart[tid * 8 + cc];
        nsq[b * S_ + s0 + tid] = nn;
        // per-block softmax partial stats over 32 rows (lanes 0..31, wave 0)
        float mb = sc;
        #pragma unroll
        for (int off = 16; off > 0; off >>= 1)
            mb = fmaxf(mb, __shfl_xor(mb, off, 32));
        const float wv = __expf(sc - mb);
        float zb = wv;
        #pragma unroll
        for (int off = 16; off > 0; off >>= 1)
            zb += __shfl_xor(zb, off, 32);
        wsb[tid] = wv;
        if (tid == 0) {
            Pbuf[(size_t)blockIdx.x * 258 + 256] = mb;
            Pbuf[(size_t)blockIdx.x * 258 + 257] = zb;
        }
    }
    __syncthreads();
    // ---- fused-attend partial: P[e] = sum_s wsb[s] * (hi+lo)[s][e]
    {
        const int pc = tid >> 5, pkg = (tid >> 3) & 3, pj = tid & 7;
        const int ub = pc * 136 + pkg * 34;
        float accp = 0.f;
        #pragma unroll 8
        for (int s = 0; s < 32; ++s) {
            const unsigned int h  = eo_hl[(size_t)(ub + s) * 8 + pj];
            const unsigned int lo = eo_hl[(size_t)(LO_UNITS + ub + s) * 8 + pj];
            accp += wsb[s] * (__uint_as_float(h << 16) + __uint_as_float(lo << 16));
        }
        Pbuf[(size_t)blockIdx.x * 258 + tid] = accp;
    }
}

// ---- Stats: per-b softmax computed once per slice-block; writes attn_map.
__global__ __launch_bounds__(256) void stats_kernel(
    const float* __restrict__ scores, const float* __restrict__ nsq,
    float* __restrict__ out)
{
    __shared__ float red[256];
    const int tid  = threadIdx.x;
    const int b    = blockIdx.x & (B_ - 1);
    const int part = blockIdx.x >> 5;      // 0..7: which 512-slice this block writes
    float v[16];
    float m = -1e30f;
    #pragma unroll
    for (int i = 0; i < 16; ++i) {
        v[i] = scores[b * S_ + i * 256 + tid];
        m = fmaxf(m, v[i]);
    }
    red[tid] = m;
    __syncthreads();
    for (int off = 128; off > 0; off >>= 1) {
        if (tid < off) red[tid] = fmaxf(red[tid], red[tid + off]);
        __syncthreads();
    }
    m = red[0];
    __syncthreads();
    float sum = 0.f;
    #pragma unroll
    for (int i = 0; i < 16; ++i) sum += __expf(v[i] - m);
    red[tid] = sum;
    __syncthreads();
    for (int off = 128; off > 0; off >>= 1) {
        if (tid < off) red[tid] += red[tid + off];
        __syncthreads();
    }
    const float inv = 1.f / red[0];
    #pragma unroll
    for (int j = 0; j < 2; ++j) {
        const int i = part * 2 + j;
        const int s = i * 256 + tid;
        const float pv = __expf(v[i] - m) * inv;
        out[B_ * E_ + b * S_ + s] = pv * sqrtf(nsq[b * S_ + s]);
    }
}

// ---- Combine: attended[b][e] from 128 per-block partials (4 MB read,
// replaces the 134 MB eo re-read).
__global__ __launch_bounds__(256) void combine_kernel(
    const float* __restrict__ Pbuf, float* __restrict__ out)
{
    __shared__ float mz[256];
    __shared__ float sc[128];
    const int tid = threadIdx.x;
    const int b   = blockIdx.x;
    if (tid < 128) mz[tid] = Pbuf[(size_t)(tid * 32 + b) * 258 + 256];
    else           mz[tid] = Pbuf[(size_t)((tid - 128) * 32 + b) * 258 + 257];
    __syncthreads();
    float m = -1e30f;
    #pragma unroll
    for (int i = 0; i < 128; ++i) m = fmaxf(m, mz[i]);
    float Z = 0.f;
    #pragma unroll
    for (int i = 0; i < 128; ++i) Z += mz[128 + i] * __expf(mz[i] - m);
    if (tid < 128) sc[tid] = __expf(mz[tid] - m);
    __syncthreads();
    float acc = 0.f;
    #pragma unroll 8
    for (int blk = 0; blk < 128; ++blk)
        acc += Pbuf[(size_t)(blk * 32 + b) * 258 + tid] * sc[blk];
    out[b * E_ + tid] = acc / Z;
}

extern "C" void kernel_launch(void* const* d_in, const int* in_sizes, int n_in,
                              void* d_out, int out_size, void* d_ws, size_t ws_size,
                              hipStream_t stream)
{
    const float* dh   = (const float*)d_in[0];  // (1,B,D)
    const float* eo   = (const float*)d_in[1];  // (S,B,E)
    const float* W    = (const float*)d_in[2];  // (A, D+E)
    const float* bias = (const float*)d_in[3];  // (A,)
    float* out = (float*)d_out;                 // [attended 8192 | attn_map 131072]
    float* ws  = (float*)d_ws;

    float* projb  = ws;                           // 8192 floats
    float* nsqb   = ws + 8192;                    // 131072 floats
    float* scores = nsqb + S_ * B_;               // 131072 floats
    float* Pbuf   = scores + S_ * B_;             // 4096*258 floats (P + m,Z per block)
    unsigned short* wepk = (unsigned short*)(Pbuf + 4096 * 258);  // 256 KB packed We

    prep_kernel    <<<96,             256, 0, stream>>>(W, dh, bias, wepk, projb);
    scores_kernel  <<<B_ * (S_ / 32), 256, 0, stream>>>(eo, wepk, projb, scores, nsqb, Pbuf);
    stats_kernel   <<<B_ * 8,         256, 0, stream>>>(scores, nsqb, out);
    combine_kernel <<<B_,             256, 0, stream>>>(Pbuf, out);
}

// Round 10
// 276.075 us; speedup vs baseline: 1.0199x; 1.0199x over previous
//
#include <hip/hip_runtime.h>
#include <math.h>

#define B_  32
#define S_  4096
#define E_  256
#define A_  256
#define DE_ 512

typedef __attribute__((ext_vector_type(8))) short short8;
typedef __attribute__((ext_vector_type(4))) float f32x4;

__device__ inline unsigned short f2bf(float x) {
    unsigned int u = __float_as_uint(x);
    u += 0x7FFFu + ((u >> 16) & 1u);      // round-to-nearest-even
    return (unsigned short)(u >> 16);
}
__device__ inline float tanh_fast(float x) {
    x = fminf(fmaxf(x, -15.f), 15.f);
    float t = __expf(2.f * x);
    return (t - 1.f) * __builtin_amdgcn_rcpf(t + 1.f);
}

// ---- Prep: block 0..63 = pack We hi/lo bf16 (fragment order),
//            block 64..95 = proj, block 96 = zero attended region.
__global__ __launch_bounds__(256) void prep_kernel(
    const float* __restrict__ W, const float* __restrict__ dh,
    const float* __restrict__ bias, unsigned short* __restrict__ wepk,
    float* __restrict__ proj, float* __restrict__ out)
{
    __shared__ float dh_lds[E_];
    const int bk  = blockIdx.x;
    const int tid = threadIdx.x;
    if (bk < 64) {
        // unit = c*2048 + plane*1024 + kg*256 + a; 8 bf16 = We[a][c*32+kg*8..+8]
        const int idx = bk * 256 + tid;
        const int c     = idx >> 11;
        const int r     = idx & 2047;
        const int plane = r >> 10;
        const int kg    = (r >> 8) & 3;
        const int a     = r & 255;
        const float* src = W + (size_t)a * DE_ + E_ + c * 32 + kg * 8;
        unsigned int pk[4];
        #pragma unroll
        for (int j = 0; j < 4; ++j) {
            float x0 = src[2 * j], x1 = src[2 * j + 1];
            unsigned int u0 = __float_as_uint(x0) & 0xFFFF0000u;
            unsigned int u1 = __float_as_uint(x1) & 0xFFFF0000u;
            if (plane) {
                unsigned short l0 = f2bf(x0 - __uint_as_float(u0));
                unsigned short l1 = f2bf(x1 - __uint_as_float(u1));
                pk[j] = (unsigned int)l0 | ((unsigned int)l1 << 16);
            } else {
                pk[j] = (u0 >> 16) | u1;
            }
        }
        *(uint4*)&wepk[(size_t)idx * 8] = make_uint4(pk[0], pk[1], pk[2], pk[3]);
    } else if (bk < 96) {
        const int b = bk - 64;
        const int a = tid;
        dh_lds[a] = dh[b * E_ + a];
        __syncthreads();
        float acc = bias[a];
        const float* wrow = W + (size_t)a * DE_;
        #pragma unroll
        for (int d = 0; d < E_; d += 4) {
            float4 w = *(const float4*)(wrow + d);
            acc += dh_lds[d] * w.x + dh_lds[d+1] * w.y
                 + dh_lds[d+2] * w.z + dh_lds[d+3] * w.w;
        }
        proj[b * A_ + a] = acc;
    } else {
        #pragma unroll
        for (int j = tid; j < B_ * E_; j += 256) out[j] = 0.f;
    }
}

// ---- Scores v13: CONTIGUOUS-READ restructure. Block = s-pair x ALL 32 b
// (rows m = sl*32+b); the eo slice is one contiguous 64 KB -> staging is a
// straight coalesced copy (per instr: 64 lanes x 16 B = 1 KB contiguous,
// one full row). eo kept fp32 in LDS (exactly 64 KB), XOR-swizzled
// (byte ^= (row&15)<<4) to break the 1KB-row-stride bank conflict; hi/lo
// bf16 conversion happens at fragment-read time (under the MFMA shadow).
// K-loop: zero barriers (single read-only buffer); We double-buffered in
// registers (chunk c+1 loads issued before chunk c's MFMAs). proj is per
// m-row (b = m&31) and loaded in the epilogue (L1-hot).
__global__ __launch_bounds__(256, 2) void scores_kernel(
    const float* __restrict__ eo, const unsigned short* __restrict__ wepk,
    const float* __restrict__ proj,
    float* __restrict__ scores, float* __restrict__ nsq)
{
    // fp32 tile: row m at pool + m*1024; 16B-granule g at (g*16)^((m&15)<<4)
    // epilogue overlay: red4 [64][66] f32 @0 (16896 B); qpart @16896
    __shared__ __align__(16) unsigned char pool[65536];

    const int tid = threadIdx.x;
    const int sp  = blockIdx.x;            // rows s = 2sp, 2sp+1 (all b)
    const int w   = tid >> 6, l = tid & 63;
    const int lq  = l >> 4,  lr = l & 15;

    // We fragment unit (16B units): c*2048 + plane*1024 + lq*256 + (w*64+nt*16+lr)
    const int wunit = lq * 256 + w * 64 + lr;

    // ---- stage: wave w copies rows w*16..w*16+15 (16 KB contiguous)
    float sq[16];
    {
        const float* src = eo + (size_t)sp * 16384 + w * 4096 + l * 4;
        #pragma unroll
        for (int q = 0; q < 16; ++q) {
            float4 v = *(const float4*)(src + q * 256);
            sq[q] = v.x*v.x + v.y*v.y + v.z*v.z + v.w*v.w;
            const int m = w * 16 + q;
            *(float4*)(pool + m * 1024 + ((l * 16) ^ ((m & 15) << 4))) = v;
        }
    }
    // ---- nsq: per-q wave butterfly (sq[q] is row w*16+q, e-quarter 4l..4l+3)
    float rowsum = 0.f;
    #pragma unroll
    for (int q = 0; q < 16; ++q) {
        float v = sq[q];
        #pragma unroll
        for (int off = 32; off > 0; off >>= 1) v += __shfl_xor(v, off, 64);
        if (l == q) rowsum = v;
    }
    if (l < 16) {
        const int m = w * 16 + l;
        nsq[(size_t)(m & 31) * S_ + 2 * sp + (m >> 5)] = rowsum;
    }

    f32x4 acc[4][4];
    #pragma unroll
    for (int i = 0; i < 4; ++i)
        #pragma unroll
        for (int j = 0; j < 4; ++j)
            acc[i][j] = (f32x4){0.f, 0.f, 0.f, 0.f};

    // ---- We chunk-0 preload (register double-buffer)
    short8 bh[4], bl[4];
    {
        const unsigned short* ws0 = wepk + (size_t)wunit * 8;
        #pragma unroll
        for (int nt = 0; nt < 4; ++nt) {
            bh[nt] = *(const short8*)(ws0 + (size_t)(nt * 16) * 8);
            bl[nt] = *(const short8*)(ws0 + (size_t)(1024 + nt * 16) * 8);
        }
    }
    __syncthreads();   // tile staged; the ONLY barrier before the epilogue

    for (int c = 0; c < 8; ++c) {
        short8 bhn[4], bln[4];
        if (c < 7) {   // issue next chunk's We loads before this chunk's MFMAs
            const unsigned short* wsn = wepk + ((size_t)(c + 1) * 2048 + wunit) * 8;
            #pragma unroll
            for (int nt = 0; nt < 4; ++nt) {
                bhn[nt] = *(const short8*)(wsn + (size_t)(nt * 16) * 8);
                bln[nt] = *(const short8*)(wsn + (size_t)(1024 + nt * 16) * 8);
            }
        }
        #pragma unroll
        for (int mt = 0; mt < 4; ++mt) {
            const int r  = mt * 16 + lr;          // A-frag row
            const int g0 = c * 8 + lq * 2;        // 16B granule of k-slice
            const unsigned char* rowp = pool + r * 1024;
            const int xr = (r & 15) << 4;
            float4 x0 = *(const float4*)(rowp + ((g0 * 16) ^ xr));
            float4 x1 = *(const float4*)(rowp + (((g0 + 1) * 16) ^ xr));
            float xs[8] = {x0.x, x0.y, x0.z, x0.w, x1.x, x1.y, x1.z, x1.w};
            union { short8 s; unsigned int u[4]; } ah, al;
            #pragma unroll
            for (int j = 0; j < 4; ++j) {
                unsigned int u0 = __float_as_uint(xs[2*j])   & 0xFFFF0000u;
                unsigned int u1 = __float_as_uint(xs[2*j+1]) & 0xFFFF0000u;
                ah.u[j] = (u0 >> 16) | u1;
                al.u[j] = (unsigned int)f2bf(xs[2*j]   - __uint_as_float(u0))
                        | ((unsigned int)f2bf(xs[2*j+1] - __uint_as_float(u1)) << 16);
            }
            #pragma unroll
            for (int nt = 0; nt < 4; ++nt) {
                acc[mt][nt] = __builtin_amdgcn_mfma_f32_16x16x32_bf16(ah.s, bh[nt], acc[mt][nt], 0, 0, 0);
                acc[mt][nt] = __builtin_amdgcn_mfma_f32_16x16x32_bf16(ah.s, bl[nt], acc[mt][nt], 0, 0, 0);
                acc[mt][nt] = __builtin_amdgcn_mfma_f32_16x16x32_bf16(al.s, bh[nt], acc[mt][nt], 0, 0, 0);
            }
        }
        if (c < 7) {
            #pragma unroll
            for (int nt = 0; nt < 4; ++nt) { bh[nt] = bhn[nt]; bl[nt] = bln[nt]; }
        }
    }
    __syncthreads();   // all LDS reads done before the epilogue overlay

    // ---- epilogue: tanh (per-row proj: b = m&31) + reduce over a
    float* red4  = (float*)pool;             // [64 a-groups][66]
    float* qpart = (float*)(pool + 16896);   // 256 floats
    #pragma unroll
    for (int mt = 0; mt < 4; ++mt) {
        #pragma unroll
        for (int rr = 0; rr < 4; ++rr) {
            const int m = mt * 16 + lq * 4 + rr;   // C/D row
            float s = 0.f;
            #pragma unroll
            for (int nt = 0; nt < 4; ++nt) {
                const float pj = proj[(size_t)(m & 31) * A_ + w * 64 + nt * 16 + lr];
                s += tanh_fast(pj + acc[mt][nt][rr]);
            }
            red4[(w * 16 + lr) * 66 + m] = s;
        }
    }
    __syncthreads();
    {   // (row = tid>>2, quarter = tid&3) sums 16 of 64 a-groups
        const int row = tid >> 2, quarter = tid & 3;
        float s = 0.f;
        #pragma unroll
        for (int j = 0; j < 16; ++j) s += red4[(quarter * 16 + j) * 66 + row];
        qpart[quarter * 64 + row] = s;
    }
    __syncthreads();
    if (tid < 64) {
        const float sc = qpart[tid] + qpart[64 + tid]
                       + qpart[128 + tid] + qpart[192 + tid];
        scores[(size_t)(tid & 31) * S_ + 2 * sp + (tid >> 5)] = sc;
    }
}

// ---- Stats: per-b softmax stats computed ONCE. Writes attn_map, and
// overwrites nsq[] in place with normalized probs (owner-thread RMW).
__global__ __launch_bounds__(256) void stats_kernel(
    const float* __restrict__ scores, float* __restrict__ nsq_pv,
    float* __restrict__ out)
{
    __shared__ float red[256];
    const int tid  = threadIdx.x;
    const int b    = blockIdx.x & (B_ - 1);
    const int part = blockIdx.x >> 5;      // 0..7: which 512-slice this block writes
    float v[16];
    float m = -1e30f;
    #pragma unroll
    for (int i = 0; i < 16; ++i) {
        v[i] = scores[b * S_ + i * 256 + tid];
        m = fmaxf(m, v[i]);
    }
    red[tid] = m;
    __syncthreads();
    for (int off = 128; off > 0; off >>= 1) {
        if (tid < off) red[tid] = fmaxf(red[tid], red[tid + off]);
        __syncthreads();
    }
    m = red[0];
    __syncthreads();
    float sum = 0.f;
    #pragma unroll
    for (int i = 0; i < 16; ++i) sum += __expf(v[i] - m);
    red[tid] = sum;
    __syncthreads();
    for (int off = 128; off > 0; off >>= 1) {
        if (tid < off) red[tid] += red[tid + off];
        __syncthreads();
    }
    const float inv = 1.f / red[0];
    #pragma unroll
    for (int j = 0; j < 2; ++j) {
        const int i = part * 2 + j;
        const int s = i * 256 + tid;
        const float pv = __expf(v[i] - m) * inv;
        out[B_ * E_ + b * S_ + s] = pv * sqrtf(nsq_pv[b * S_ + s]);
        nsq_pv[b * S_ + s] = pv;
    }
}

// ---- Attend v13: CONTIGUOUS streaming. Block = 16 s x all 32 b: reads
// 512 KB fully sequential (per instr: 64 lanes x 4B within a 1KB row).
// acc[32] per thread (one per b); 256 atomicAdds/address total (R0-proven).
__global__ __launch_bounds__(256) void attend_kernel(
    const float* __restrict__ eo, const float* __restrict__ pv,
    float* __restrict__ out)
{
    const int j = blockIdx.x;          // 256 blocks x 16 s
    const int e = threadIdx.x;
    float acc[32];
    #pragma unroll
    for (int b = 0; b < 32; ++b) acc[b] = 0.f;
    const float* base = eo + (size_t)j * 16 * (B_ * E_);
    for (int sl = 0; sl < 16; ++sl) {
        const int s = j * 16 + sl;
        #pragma unroll
        for (int b = 0; b < 32; ++b) {
            acc[b] = fmaf(pv[(size_t)b * S_ + s],
                          base[(size_t)(sl * 32 + b) * E_ + e], acc[b]);
        }
    }
    #pragma unroll
    for (int b = 0; b < 32; ++b) atomicAdd(&out[b * E_ + e], acc[b]);
}

extern "C" void kernel_launch(void* const* d_in, const int* in_sizes, int n_in,
                              void* d_out, int out_size, void* d_ws, size_t ws_size,
                              hipStream_t stream)
{
    const float* dh   = (const float*)d_in[0];  // (1,B,D)
    const float* eo   = (const float*)d_in[1];  // (S,B,E)
    const float* W    = (const float*)d_in[2];  // (A, D+E)
    const float* bias = (const float*)d_in[3];  // (A,)
    float* out = (float*)d_out;                 // [attended 8192 | attn_map 131072]
    float* ws  = (float*)d_ws;

    float* projb  = ws;                           // 8192 floats
    float* nsqb   = ws + 8192;                    // 131072 floats (nsq, then pv in-place)
    float* scores = nsqb + S_ * B_;               // 131072 floats
    unsigned short* wepk = (unsigned short*)(scores + S_ * B_);  // 256 KB packed We

    prep_kernel   <<<97,        256, 0, stream>>>(W, dh, bias, wepk, projb, out);
    scores_kernel <<<S_ / 2,    256, 0, stream>>>(eo, wepk, projb, scores, nsqb);
    stats_kernel  <<<B_ * 8,    256, 0, stream>>>(scores, nsqb, out);
    attend_kernel <<<S_ / 16,   256, 0, stream>>>(eo, nsqb, out);
}